// Round 6
// baseline (165.891 us; speedup 1.0000x reference)
//
#include <hip/hip_runtime.h>

// Problem constants (fixed by reference: B=64, T=1024, D=256)
constexpr int Bn = 64;
constexpr int Tn = 1024;
constexpr int Dn = 256;

constexpr int TPB   = 64;          // ONE wave per workgroup: no s_barrier anywhere
constexpr int QUADS = 4;           // 2x2 quadrants of the 64x64 cross matrix
constexpr int NBLK  = Tn * QUADS;  // 4096 wave-blocks
constexpr int CH    = 32;          // K per chunk (128 B granules per row)
constexpr int NCH   = Dn / CH;     // 8 chunks
constexpr int NBIN  = 64;          // partial-sum bins

using short8 = __attribute__((ext_vector_type(8))) short;   // 8 bf16 — MFMA A/B frag
using f32x16 = __attribute__((ext_vector_type(16))) float;  // MFMA 32x32 accumulator

__device__ __forceinline__ float dot4(const float4& a, const float4& b) {
    return a.x * b.x + a.y * b.y + a.z * b.z + a.w * b.w;
}

// fp32 -> bf16 bits, round-to-nearest-even
__device__ __forceinline__ unsigned int bfbits(float x) {
    unsigned int u = __builtin_bit_cast(unsigned int, x);
    return (u + 0x7FFFu + ((u >> 16) & 1u)) >> 16;
}
__device__ __forceinline__ unsigned int pack_bf2(float lo, float hi) {
    return bfbits(lo) | (bfbits(hi) << 16);
}

// Direct global->LDS 16B copy: prefetch depth lives in the per-wave vmcnt queue, 0 VGPRs.
__device__ __forceinline__ void gload16(const float* g, float* l) {
    __builtin_amdgcn_global_load_lds(
        (const __attribute__((address_space(1))) void*)g,
        (__attribute__((address_space(3))) void*)l,
        16, 0, 0);
}

// Per-wave counted wait (T4). "memory" clobber orders the following ds_reads;
// sched_barrier(0) per rule #18 keeps the scheduler from drifting ops across.
#define VM_WAIT(N) do {                                         \
    asm volatile("s_waitcnt vmcnt(" #N ")" ::: "memory");       \
    __builtin_amdgcn_sched_barrier(0);                          \
} while (0)

__global__ __launch_bounds__(TPB, 4)   // cap 128 VGPR
void cmfm_main(const float* __restrict__ fv, const float* __restrict__ fa,
               const int* __restrict__ labels, float* __restrict__ acc)
{
    // Ring of 2 chunk buffers. Combined layout per chunk: 32 rows x 256 B
    // (V 8 16B-slots + A 8 16B-slots per row), physical slot = logical ^ (row&15)
    // -> both ds_write (via pre-swizzled global source, rule #21) and ds_read_b128
    // land at free 2-way bank aliasing.
    __shared__ __align__(16) float buf[2][32 * 64];   // 2 x 8 KB

    const int lane = threadIdx.x;
    const int bid  = blockIdx.x;

    // Bijective XCD swizzle (T1; 4096 % 8 == 0): all 4 quadrants of a t land on the
    // SAME XCD at adjacent lids -> the 2x quadrant read amplification hits L2.
    const int lid  = (bid & 7) * (NBLK / 8) + (bid >> 3);
    const int t    = lid >> 2;
    const int quad = lid & 3;
    const int i0   = (quad >> 1) * 32;     // V-row block (C rows)
    const int j0   = (quad & 1) * 32;      // A-row block (C cols)
    const int mrow = lane & 31;
    const int half = lane >> 5;
    const bool diag = (i0 == j0);
    const int key  = mrow & 15;            // read swizzle key

    // Staging map (8 gload16/chunk): LDS byte n*1024 + lane*16 ->
    // row r = n*4 + lane/16, phys slot p = lane&15, logical l = p ^ (r&15).
    const int sr = lane >> 4;              // row offset within 4-row group
    const int sp = lane & 15;              // physical slot

    f32x16 C;
    #pragma unroll
    for (int r = 0; r < 16; ++r) C[r] = 0.f;

    float sqv = 0.f, sqa = 0.f, dva = 0.f;

    #define STAGE(c, b) do {                                                         \
        _Pragma("unroll")                                                            \
        for (int n = 0; n < 8; ++n) {                                                \
            const int r  = n * 4 + sr;                                               \
            const int l  = sp ^ (r & 15);                                            \
            const int rowg = ((l < 8) ? i0 : j0) + r;                                \
            const size_t goff = ((size_t)rowg * Tn + t) * Dn + (c) * CH + (l & 7) * 4; \
            const float* src = (l < 8) ? (fv + goff) : (fa + goff);                  \
            gload16(src, &buf[b][n * 256 + lane * 4]);                               \
        }                                                                            \
    } while (0)

    STAGE(0, 0);                           // prologue: 2 chunks in flight (16 instrs)
    STAGE(1, 1);

    #pragma unroll
    for (int c = 0; c < NCH; ++c) {
        const int b = c & 1;
        if (c < NCH - 1) { VM_WAIT(8); }   // chunk c landed; chunk c+1 stays in flight
        else            { VM_WAIT(0); }

        // consume chunk c: 2 K=16 steps; fp32 norms + RNE bf16 pack + MFMA
        #pragma unroll
        for (int s = 0; s < 2; ++s) {
            const int lV = s * 4 + 2 * half;       // V logical slots (this lane's k-slice)
            const int lA = 8 + s * 4 + 2 * half;   // A logical slots
            const unsigned rb = (unsigned)mrow * 64;
            const float4 v0 = *reinterpret_cast<const float4*>(&buf[b][rb + (((lV    ) ^ key) << 2)]);
            const float4 v1 = *reinterpret_cast<const float4*>(&buf[b][rb + (((lV + 1) ^ key) << 2)]);
            const float4 a0 = *reinterpret_cast<const float4*>(&buf[b][rb + (((lA    ) ^ key) << 2)]);
            const float4 a1 = *reinterpret_cast<const float4*>(&buf[b][rb + (((lA + 1) ^ key) << 2)]);

            sqv += dot4(v0, v0) + dot4(v1, v1);    // per-row partials over this k-slice
            sqa += dot4(a0, a0) + dot4(a1, a1);
            if (diag) dva += dot4(v0, a0) + dot4(v1, a1);

            union { short8 s8; uint4 u4; } av, bv;
            av.u4.x = pack_bf2(v0.x, v0.y); av.u4.y = pack_bf2(v0.z, v0.w);
            av.u4.z = pack_bf2(v1.x, v1.y); av.u4.w = pack_bf2(v1.z, v1.w);
            bv.u4.x = pack_bf2(a0.x, a0.y); bv.u4.y = pack_bf2(a0.z, a0.w);
            bv.u4.z = pack_bf2(a1.x, a1.y); bv.u4.w = pack_bf2(a1.z, a1.w);
            C = __builtin_amdgcn_mfma_f32_32x32x16_bf16(av.s8, bv.s8, C, 0, 0, 0);
        }

        // refill this buffer with chunk c+2 (packs above already forced the ds_reads
        // to complete; lgkm drain + sched wall make the overwrite provably safe)
        if (c + 2 < NCH) {
            asm volatile("s_waitcnt lgkmcnt(0)" ::: "memory");
            __builtin_amdgcn_sched_barrier(0);
            STAGE(c + 2, b);
        }
    }
    #undef STAGE

    // ---- row norms: halves hold disjoint k-subsets -> one cross-half combine ----
    sqv += __shfl_xor(sqv, 32);
    sqa += __shfl_xor(sqa, 32);
    const float rv = 1.f / fmaxf(sqrtf(sqv), 1e-8f);   // row i0+mrow
    const float ra = 1.f / fmaxf(sqrtf(sqa), 1e-8f);   // row j0+mrow

    // ---- aligned-pair term: diagonal quadrants only (each row once per t) ----
    float pos = 0.f, neg = 0.f;
    if (diag) {
        dva += __shfl_xor(dva, 32);
        const float cosd = dva * rv * ra;
        if (half == 0) {
            if (labels[i0 + mrow] == 0) pos = 1.f - cosd;   // d_bt = 1 - cos
            else                        neg = cosd;          // (1 - d_bt) = cos
        }
    }

    // ---- cross term: scale rv_i * ra_j, drop diagonal ----
    // C/D mapping (m74/m101): col = lane&31, row = (reg&3) + 8*(reg>>2) + 4*(lane>>5)
    float od = 0.f;
    #pragma unroll
    for (int r = 0; r < 16; ++r) {
        const int ri = (r & 3) + 8 * (r >> 2) + 4 * half;
        const float rvi = __shfl(rv, ri);      // rv of row i0+ri lives on lane ri
        float cc = C[r];
        if (diag && ri == mrow) cc = 0.f;      // i == j diagonal
        od += rvi * ra * cc;
    }

    // ---- wave reduce + 3 atomics into this block's bin ----
    #pragma unroll
    for (int off = 1; off < 64; off <<= 1) {
        pos += __shfl_xor(pos, off);
        neg += __shfl_xor(neg, off);
        od  += __shfl_xor(od, off);
    }
    if (lane == 0) {
        float* bin = acc + (size_t)(bid & (NBIN - 1)) * 4;
        atomicAdd(bin + 0, pos);
        atomicAdd(bin + 1, neg);
        atomicAdd(bin + 2, od);
    }
}

__global__ void cmfm_final(const int* __restrict__ labels, const float* __restrict__ acc,
                           float* __restrict__ out) {
    const int l = threadIdx.x;     // 64 threads = 64 bins = 64 labels
    float p = acc[l * 4 + 0];
    float n = acc[l * 4 + 1];
    float o = acc[l * 4 + 2];
    float npf = (labels[l] == 0) ? 1.f : 0.f;
    #pragma unroll
    for (int off = 1; off < 64; off <<= 1) {
        p += __shfl_xor(p, off);
        n += __shfl_xor(n, off);
        o += __shfl_xor(o, off);
        npf += __shfl_xor(npf, off);
    }
    if (l == 0) {
        const int np = (int)(npf + 0.5f);
        const float cnt_pos = (float)np * (float)Tn;
        const float cnt_neg = (float)(Bn - np) * (float)Tn + (float)Bn * (float)(Bn - 1);
        float loss = 0.f;
        if (np > 0) loss += 2.0f * p / cnt_pos;                  // ALPHA
        loss += (2.0f * n + 1.0f * o / (float)Tn) / cnt_neg;     // BETA, GAMMA
        out[0] = loss;
    }
}

extern "C" void kernel_launch(void* const* d_in, const int* in_sizes, int n_in,
                              void* d_out, int out_size, void* d_ws, size_t ws_size,
                              hipStream_t stream) {
    const float* fv     = (const float*)d_in[0];
    const float* fa     = (const float*)d_in[1];
    const int*   labels = (const int*)d_in[2];
    float* acc = (float*)d_ws;        // 64 bins x {pos, neg, cross, pad}
    float* out = (float*)d_out;

    hipMemsetAsync(acc, 0, NBIN * 4 * sizeof(float), stream);
    cmfm_main<<<NBLK, TPB, 0, stream>>>(fv, fa, labels, acc);
    cmfm_final<<<1, 64, 0, stream>>>(labels, acc, out);
}

// Round 7
// 156.076 us; speedup vs baseline: 1.0629x; 1.0629x over previous
//
#include <hip/hip_runtime.h>

// Problem constants (fixed by reference: B=64, T=1024, D=256)
constexpr int Bn = 64;
constexpr int Tn = 1024;
constexpr int Dn = 256;

constexpr int TPB  = 256;       // 4 waves
constexpr int NBLK = Tn;        // one timestep per block; 4 blocks/CU (32KB LDS), all resident
constexpr int CH   = 16;        // K per chunk = one K=16 MFMA step
constexpr int NCH  = Dn / CH;   // 16 chunks
constexpr int NBIN = 64;        // partial-sum bins

using short8 = __attribute__((ext_vector_type(8))) short;   // 8 bf16 — MFMA A/B frag
using f32x16 = __attribute__((ext_vector_type(16))) float;  // MFMA 32x32 accumulator

__device__ __forceinline__ float dot4(const float4& a, const float4& b) {
    return a.x * b.x + a.y * b.y + a.z * b.z + a.w * b.w;
}

// fp32 -> bf16 bits, round-to-nearest-even
__device__ __forceinline__ unsigned int bfbits(float x) {
    unsigned int u = __builtin_bit_cast(unsigned int, x);
    return (u + 0x7FFFu + ((u >> 16) & 1u)) >> 16;
}
__device__ __forceinline__ unsigned int pack_bf2(float lo, float hi) {
    return bfbits(lo) | (bfbits(hi) << 16);
}

// Direct global->LDS 16B copy: prefetch depth lives in the vmcnt queue, 0 VGPRs.
__device__ __forceinline__ void gload16(const float* g, float* l) {
    __builtin_amdgcn_global_load_lds(
        (const __attribute__((address_space(1))) void*)g,
        (__attribute__((address_space(3))) void*)l, 16, 0, 0);
}

// ONE barrier per chunk (T3/T4): counted vmcnt (chunk c landed for THIS wave) then
// s_barrier (so it landed for ALL waves). Never drains the 2 lookahead chunks.
// sched_barrier(0) walls per rule #18.
#define SYNC_AFTER_VMWAIT(N) do {                               \
    asm volatile("s_waitcnt vmcnt(" #N ")" ::: "memory");       \
    __builtin_amdgcn_sched_barrier(0);                          \
    __builtin_amdgcn_s_barrier();                               \
    __builtin_amdgcn_sched_barrier(0);                          \
} while (0)

__global__ __launch_bounds__(TPB, 4)   // cap 128 VGPR -> 4 blocks/CU (16 waves/CU)
void cmfm_main(const float* __restrict__ fv, const float* __restrict__ fa,
               const int* __restrict__ labels, float* __restrict__ acc)
{
    // 4-region ring, 8 KB each. Region layout: 32 lines x 256 B; line L holds rows
    // {2L, 2L+1} x {V,A} as 16 16B-slots, physical slot = logical ^ (L&15), where
    // logical = 8*(row&1) + cat (cat 0-3 = V k-slots, 4-7 = A k-slots).
    // -> gload dest is LINEAR (perm folded into global source, rule #21) and the
    //    fragment ds_read_b128s land 2 lanes/slot = free 2-way aliasing.
    __shared__ __align__(16) float buf[4][2048];
    __shared__ float rvs[Bn], ras[Bn];
    __shared__ float wred[3][TPB / 64];

    const int tid  = threadIdx.x;
    const int lane = tid & 63;
    const int wave = tid >> 6;
    const int t    = blockIdx.x;

    // MFMA geometry: 4 waves -> 2x2 quadrants of the 64x64 cross matrix
    const int i0   = (wave >> 1) * 32;
    const int j0   = (wave & 1) * 32;
    const int mrow = lane & 31;
    const int half = lane >> 5;
    const bool diag = (i0 == j0);      // waves 0 and 3 own the norm accumulation

    // ---- per-thread staging source pointers (2 gload16 per chunk; offset = c*64B imm) ----
    const float* sp0; const float* sp1;
    {
        #pragma unroll
        for (int n = 0; n < 2; ++n) {
            const int u    = n * 256 + tid;      // 16B unit within region (0..511)
            const int line = u >> 4;
            const int pos  = u & 15;
            const int l    = pos ^ (line & 15);  // logical slot (involution)
            const int r    = 2 * line + (l >> 3);
            const int cat  = l & 7;
            const float* base = (cat < 4) ? fv : fa;
            const float* p = base + ((size_t)r * Tn + t) * Dn + (cat & 3) * 4;
            if (n == 0) sp0 = p; else sp1 = p;
        }
    }

    // ---- per-lane fragment read offsets (16B units, constant all chunks) ----
    const int rV = i0 + mrow, rA = j0 + mrow;
    const int lnV = rV >> 1, lnA = rA >> 1;
    const int lV = 8 * (rV & 1) + 2 * half;          // V logical cats lV, lV+1
    const int lA = 8 * (rA & 1) + 4 + 2 * half;      // A logical cats lA, lA+1
    const int uV0 = lnV * 16 + ((lV    ) ^ (lnV & 15));
    const int uV1 = lnV * 16 + ((lV + 1) ^ (lnV & 15));
    const int uA0 = lnA * 16 + ((lA    ) ^ (lnA & 15));
    const int uA1 = lnA * 16 + ((lA + 1) ^ (lnA & 15));

    f32x16 C;
    #pragma unroll
    for (int r = 0; r < 16; ++r) C[r] = 0.f;

    float sqv = 0.f, sqa = 0.f, dva = 0.f;

    #define STAGE(c) do {                                       \
        float* dst = &buf[(c) & 3][0];                          \
        gload16(sp0 + (c) * CH, dst + tid * 4);                 \
        gload16(sp1 + (c) * CH, dst + 1024 + tid * 4);          \
    } while (0)

    STAGE(0); STAGE(1); STAGE(2);      // prologue: 3 chunks (6 vmem/wave) in flight

    #pragma unroll
    for (int c = 0; c < NCH; ++c) {
        if      (c <  NCH - 2) SYNC_AFTER_VMWAIT(4);   // steady: 2 chunks stay in flight
        else if (c == NCH - 2) SYNC_AFTER_VMWAIT(2);
        else                   SYNC_AFTER_VMWAIT(0);

        // consume chunk c: one K=16 step; fp32 norms (diag) + RNE bf16 pack + MFMA
        const float* rb = &buf[c & 3][0];
        const float4 v0 = *reinterpret_cast<const float4*>(rb + uV0 * 4);
        const float4 v1 = *reinterpret_cast<const float4*>(rb + uV1 * 4);
        const float4 a0 = *reinterpret_cast<const float4*>(rb + uA0 * 4);
        const float4 a1 = *reinterpret_cast<const float4*>(rb + uA1 * 4);

        if (diag) {                    // each (row,k) hits exactly one diag-wave lane
            sqv += dot4(v0, v0) + dot4(v1, v1);
            sqa += dot4(a0, a0) + dot4(a1, a1);
            dva += dot4(v0, a0) + dot4(v1, a1);
        }

        union { short8 s8; uint4 u4; } av, bv;
        av.u4.x = pack_bf2(v0.x, v0.y); av.u4.y = pack_bf2(v0.z, v0.w);
        av.u4.z = pack_bf2(v1.x, v1.y); av.u4.w = pack_bf2(v1.z, v1.w);
        bv.u4.x = pack_bf2(a0.x, a0.y); bv.u4.y = pack_bf2(a0.z, a0.w);
        bv.u4.z = pack_bf2(a1.x, a1.y); bv.u4.w = pack_bf2(a1.z, a1.w);
        C = __builtin_amdgcn_mfma_f32_32x32x16_bf16(av.s8, bv.s8, C, 0, 0, 0);

        // refill region (c-1)&3 with chunk c+3: safe after barrier c (ring>=3: every
        // wave used -> retired its chunk c-1 ds_reads before passing barrier c)
        if (c + 3 < NCH) STAGE(c + 3);
    }
    #undef STAGE

    // ---- norms (diag waves): halves hold disjoint k-subsets -> one combine ----
    float pos = 0.f, neg = 0.f;
    if (diag) {
        sqv += __shfl_xor(sqv, 32);
        sqa += __shfl_xor(sqa, 32);
        dva += __shfl_xor(dva, 32);
        const float rv = 1.f / fmaxf(sqrtf(sqv), 1e-8f);
        const float ra = 1.f / fmaxf(sqrtf(sqa), 1e-8f);
        if (half == 0) {
            rvs[rV] = rv;              // wave0 rows 0-31, wave3 rows 32-63
            ras[rV] = ra;
            const float cosd = dva * rv * ra;   // aligned-pair cosine (exact fp32)
            if (labels[rV] == 0) pos = 1.f - cosd;   // d_bt = 1 - cos
            else                 neg = cosd;          // (1 - d_bt) = cos
        }
    }
    __syncthreads();                   // nothing in flight; plain barrier is fine

    // ---- cross term: scale rv_i * ra_j, drop diagonal ----
    // C/D mapping (m74/m101): col = lane&31, row = (reg&3) + 8*(reg>>2) + 4*(lane>>5)
    const float raj = ras[j0 + mrow];
    float od = 0.f;
    #pragma unroll
    for (int r = 0; r < 16; ++r) {
        const int ri = (r & 3) + 8 * (r >> 2) + 4 * half;
        float cc = C[r];
        if (diag && ri == mrow) cc = 0.f;       // i == j diagonal
        od += rvs[i0 + ri] * raj * cc;
    }

    // ---- block reduce + 3 atomics into this block's bin ----
    #pragma unroll
    for (int off = 1; off < 64; off <<= 1) {
        pos += __shfl_xor(pos, off);
        neg += __shfl_xor(neg, off);
        od  += __shfl_xor(od, off);
    }
    if (lane == 0) { wred[0][wave] = pos; wred[1][wave] = neg; wred[2][wave] = od; }
    __syncthreads();
    if (tid == 0) {
        float p = 0.f, n = 0.f, o = 0.f;
        #pragma unroll
        for (int w = 0; w < TPB / 64; ++w) { p += wred[0][w]; n += wred[1][w]; o += wred[2][w]; }
        float* bin = acc + (size_t)(blockIdx.x & (NBIN - 1)) * 4;
        atomicAdd(bin + 0, p);
        atomicAdd(bin + 1, n);
        atomicAdd(bin + 2, o);
    }
}

__global__ void cmfm_final(const int* __restrict__ labels, const float* __restrict__ acc,
                           float* __restrict__ out) {
    const int l = threadIdx.x;     // 64 threads = 64 bins = 64 labels
    float p = acc[l * 4 + 0];
    float n = acc[l * 4 + 1];
    float o = acc[l * 4 + 2];
    float npf = (labels[l] == 0) ? 1.f : 0.f;
    #pragma unroll
    for (int off = 1; off < 64; off <<= 1) {
        p += __shfl_xor(p, off);
        n += __shfl_xor(n, off);
        o += __shfl_xor(o, off);
        npf += __shfl_xor(npf, off);
    }
    if (l == 0) {
        const int np = (int)(npf + 0.5f);
        const float cnt_pos = (float)np * (float)Tn;
        const float cnt_neg = (float)(Bn - np) * (float)Tn + (float)Bn * (float)(Bn - 1);
        float loss = 0.f;
        if (np > 0) loss += 2.0f * p / cnt_pos;                  // ALPHA
        loss += (2.0f * n + 1.0f * o / (float)Tn) / cnt_neg;     // BETA, GAMMA
        out[0] = loss;
    }
}

extern "C" void kernel_launch(void* const* d_in, const int* in_sizes, int n_in,
                              void* d_out, int out_size, void* d_ws, size_t ws_size,
                              hipStream_t stream) {
    const float* fv     = (const float*)d_in[0];
    const float* fa     = (const float*)d_in[1];
    const int*   labels = (const int*)d_in[2];
    float* acc = (float*)d_ws;        // 64 bins x {pos, neg, cross, pad}
    float* out = (float*)d_out;

    hipMemsetAsync(acc, 0, NBIN * 4 * sizeof(float), stream);
    cmfm_main<<<NBLK, TPB, 0, stream>>>(fv, fa, labels, acc);
    cmfm_final<<<1, 64, 0, stream>>>(labels, acc, out);
}